// Round 12
// baseline (87.698 us; speedup 1.0000x reference)
//
#include <hip/hip_runtime.h>
#include <hip/hip_bf16.h>
#include <math.h>

#define BB 2
#define CC 128
#define HH 60
#define WW 80
#define NN 3072
#define TT 16.0f
#define SS 81
#define HW (HH*WW)
#define NTILE 24   // 3072/128
#define LDA 136    // 128 + 8 bf16 pad (k_corr tiles)
#define XN 12
#define YN 10
#define PSTRIDE 128   // floats per point in ws (120 used)
#define ROWB 272      // 128 f16 + 16 pad bytes per window row (16B aligned)

typedef __attribute__((ext_vector_type(8))) short short8;
typedef __attribute__((ext_vector_type(4))) float f32x4;
typedef _Float16 hf;
typedef _Float16 __attribute__((ext_vector_type(2))) h2;
typedef _Float16 __attribute__((ext_vector_type(8))) h8;

// DPP cross-lane terms (VALU pipe, no DS). dpp_ctrl must be a literal -> template.
template<int CTRL>
__device__ __forceinline__ float dppterm(float s){
    return __int_as_float(__builtin_amdgcn_update_dpp(0, __float_as_int(s), CTRL, 0xf, 0xf, true));
}
__device__ __forceinline__ float red8_add(float s){
    s += dppterm<0xB1>(s); s += dppterm<0x4E>(s); s += dppterm<0x141>(s); return s;
}
__device__ __forceinline__ float red16_add(float s){
    s += dppterm<0xB1>(s); s += dppterm<0x4E>(s); s += dppterm<0x141>(s); s += dppterm<0x140>(s); return s;
}
__device__ __forceinline__ float swz16_add(float s){
    return s + __int_as_float(__builtin_amdgcn_ds_swizzle(__float_as_int(s), 0x401F));
}
__device__ __forceinline__ float red64_add(float s){
    s = red16_add(s); s = swz16_add(s); s += __shfl_xor(s, 32); return s;
}
__device__ __forceinline__ float red64_max(float s){
    s = fmaxf(s, dppterm<0xB1>(s)); s = fmaxf(s, dppterm<0x4E>(s));
    s = fmaxf(s, dppterm<0x141>(s)); s = fmaxf(s, dppterm<0x140>(s));
    s = fmaxf(s, __int_as_float(__builtin_amdgcn_ds_swizzle(__float_as_int(s), 0x401F)));
    s = fmaxf(s, __shfl_xor(s, 32));
    return s;
}

__device__ __forceinline__ void bsetup(float cn, int L, int& i0, int& i1, float& w){
    float x = (cn + 1.0f) * 0.5f * (float)(L - 1);
    float x0 = floorf(x);
    w = x - x0;
    int xi = (int)x0;
    i0 = xi < 0 ? 0 : (xi > L - 1 ? L - 1 : xi);
    i1 = (i0 + 1 > L - 1) ? L - 1 : (i0 + 1);
}

// Transpose + per-pixel L2 stats -> f16 raw map + f16 T*normalized map.
__global__ __launch_bounds__(256) void k_normT(
        const float* __restrict__ xf1, const float* __restrict__ xf2,
        hf* __restrict__ xf1r, hf* __restrict__ xf2r,
        hf* __restrict__ xf1t, hf* __restrict__ xf2t){
    int idx = blockIdx.x;
    int map = idx / (BB*(HW/32));
    int rem = idx % (BB*(HW/32));
    int b   = rem / (HW/32);
    int hw0 = (rem % (HW/32)) * 32;
    const float* src = (map ? xf2 : xf1) + (size_t)b*CC*HW + hw0;
    hf* dstR = (map ? xf2r : xf1r) + ((size_t)(b*HW + hw0))*CC;
    hf* dstT = (map ? xf2t : xf1t) + ((size_t)(b*HW + hw0))*CC;

    __shared__ float tile[CC][33];
    int tid = threadIdx.x;
    {
        int p = tid & 31, c0 = tid >> 5;
        #pragma unroll
        for(int i=0;i<16;i++){
            int c = i*8 + c0;
            tile[c][p] = src[(size_t)c*HW + p];
        }
    }
    __syncthreads();
    int q = tid >> 3, l = tid & 7;
    float v[16];
    float ss = 0.f;
    #pragma unroll
    for(int k=0;k<16;k++){ v[k] = tile[l*16+k][q]; ss += v[k]*v[k]; }
    ss = red8_add(ss);
    float inv = 1.0f / sqrtf(ss + 1e-12f);
    float tsc = TT * inv;
    union { hf h[16]; uint4 u[2]; } R, T;
    #pragma unroll
    for(int k=0;k<16;k++){ R.h[k] = (hf)v[k]; T.h[k] = (hf)(v[k]*tsc); }
    uint4* oR = (uint4*)(dstR + (size_t)q*CC + l*16);
    uint4* oT = (uint4*)(dstT + (size_t)q*CC + l*16);
    oR[0] = R.u[0]; oR[1] = R.u[1];
    oT[0] = T.u[0]; oT[1] = T.u[1];
}

// Bilinear sample RAW transposed f16 map, L2-normalize -> bf16 features + denormed
// coords. 4 independent wave-queries per 256-thread block.
__global__ __launch_bounds__(256) void k_feats(
        const hf* __restrict__ xf1r, const hf* __restrict__ xf2r,
        const float* __restrict__ c1n, const float* __restrict__ c2n,
        __hip_bfloat16* __restrict__ f1b, __hip_bfloat16* __restrict__ f2b,
        float* __restrict__ o_coord1, float* __restrict__ o_coord2,
        const int* __restrict__ h1I, const int* __restrict__ w1I,
        const int* __restrict__ h2I, const int* __restrict__ w2I){
    int tid = threadIdx.x;
    int gid = blockIdx.x*4 + (tid >> 6);
    int dir = gid / (BB*NN);
    int bn  = gid % (BB*NN);
    int b = bn / NN;
    const hf* raw = dir ? xf2r : xf1r;
    const float* cn = dir ? c2n : c1n;
    __hip_bfloat16* fOutB = dir ? f2b : f1b;
    float* coordOut = dir ? o_coord2 : o_coord1;
    const int* hI = dir ? h2I : h1I;
    const int* wI = dir ? w2I : w1I;

    int t = tid & 63;   // channels 2t,2t+1
    float cnx = cn[(size_t)bn*2+0], cny = cn[(size_t)bn*2+1];
    int x0,x1,y0,y1; float wx,wy;
    bsetup(cnx, WW, x0,x1,wx);
    bsetup(cny, HH, y0,y1,wy);
    const hf* base = raw + (size_t)(b*HW)*CC;
    const uint* r00 = (const uint*)(base + (size_t)(y0*WW+x0)*CC) + t;
    const uint* r01 = (const uint*)(base + (size_t)(y0*WW+x1)*CC) + t;
    const uint* r10 = (const uint*)(base + (size_t)(y1*WW+x0)*CC) + t;
    const uint* r11 = (const uint*)(base + (size_t)(y1*WW+x1)*CC) + t;
    union { uint u; h2 v; } u00, u01, u10, u11;
    u00.u = *r00; u01.u = *r01; u10.u = *r10; u11.u = *r11;
    float w00=(1.f-wx)*(1.f-wy), w01=wx*(1.f-wy), w10=(1.f-wx)*wy, w11=wx*wy;
    float fx = w00*(float)u00.v.x + w01*(float)u01.v.x + w10*(float)u10.v.x + w11*(float)u11.v.x;
    float fy = w00*(float)u00.v.y + w01*(float)u01.v.y + w10*(float)u10.v.y + w11*(float)u11.v.y;
    float ss = fx*fx + fy*fy;
    ss = red64_add(ss);
    float inv = 1.0f / sqrtf(ss + 1e-12f);
    unsigned short blo = __bfloat16_as_ushort(__float2bfloat16(fx*inv));
    unsigned short bhi = __bfloat16_as_ushort(__float2bfloat16(fy*inv));
    ((uint*)(fOutB + (size_t)bn*CC))[t] = ((uint)bhi << 16) | blo;
    if(t==0){
        float h=(float)hI[0], w=(float)wI[0];
        coordOut[(size_t)bn*2+0] = (cnx+1.0f)*0.5f*(w-1.0f);
        coordOut[(size_t)bn*2+1] = (cny+1.0f)*0.5f*(h-1.0f);
    }
}

// Fused correlation v5 (unchanged).
__global__ __launch_bounds__(512,4) void k_corr(
        const __hip_bfloat16* __restrict__ f1b, const __hip_bfloat16* __restrict__ f2b,
        const float* __restrict__ c1n, const float* __restrict__ c2n,
        float* __restrict__ wsP,
        const int* __restrict__ h1I, const int* __restrict__ w1I,
        const int* __restrict__ h2I, const int* __restrict__ w2I){
    const int nwg = BB*NTILE*NTILE;
    int blk = blockIdx.x;
    blk = (blk & 7)*(nwg/8) + (blk >> 3);
    int b   = blk / (NTILE*NTILE);
    int rem = blk % (NTILE*NTILE);
    int nt = rem / NTILE, mt = rem % NTILE;
    int n0 = nt*128, m0 = mt*128;
    int tid = threadIdx.x;
    int lane = tid & 63, wid = tid >> 6;
    int wr = wid >> 1, wc = wid & 1;
    int lr = lane & 15, lh = lane >> 4;

    __shared__ __align__(16) unsigned short smem[2*128*LDA];
    unsigned short* As = smem;
    unsigned short* Bs = smem + 128*LDA;
    float* parts = (float*)smem;
    const int COLOFF = 2*128*8;

    {
        const unsigned short* gA = (const unsigned short*)f1b + ((size_t)b*NN + n0)*CC;
        const unsigned short* gB = (const unsigned short*)f2b + ((size_t)b*NN + m0)*CC;
        #pragma unroll
        for(int it=0; it<4; ++it){
            int idx = tid + it*512;
            int r = idx >> 4, q = idx & 15;
            *(uint4*)(As + r*LDA + q*8) = *(const uint4*)(gA + r*CC + q*8);
            *(uint4*)(Bs + r*LDA + q*8) = *(const uint4*)(gB + r*CC + q*8);
        }
    }

    float2 c2v[4], c1v[8];
    #pragma unroll
    for(int j=0;j<4;j++)
        c2v[j] = ((const float2*)c2n)[(size_t)b*NN + m0 + wc*64 + j*16 + lr];
    #pragma unroll
    for(int i=0;i<2;i++)
        #pragma unroll
        for(int r=0;r<4;r++)
            c1v[i*4+r] = ((const float2*)c1n)[(size_t)b*NN + n0 + wr*32 + i*16 + lh*4 + r];

    __syncthreads();

    f32x4 acc[2][4] = {};
    const unsigned short* aBase = As + (wr*32 + lr)*LDA + lh*8;
    const unsigned short* bBase = Bs + (wc*64 + lr)*LDA + lh*8;
    #pragma unroll
    for(int ks=0; ks<4; ++ks){
        short8 afr[2], bfr[4];
        #pragma unroll
        for(int i=0;i<2;i++) afr[i] = *(const short8*)(aBase + i*16*LDA + ks*32);
        #pragma unroll
        for(int j=0;j<4;j++) bfr[j] = *(const short8*)(bBase + j*16*LDA + ks*32);
        #pragma unroll
        for(int i=0;i<2;i++)
            #pragma unroll
            for(int j=0;j<4;j++)
                acc[i][j] = __builtin_amdgcn_mfma_f32_16x16x32_bf16(afr[i], bfr[j], acc[i][j], 0,0,0);
    }
    __syncthreads();

    const float TL2E = 23.08312035f;
    float h1f=(float)h1I[0], w1f=(float)w1I[0], h2f=(float)h2I[0], w2f=(float)w2I[0];
    float sx2 = 0.5f*(w2f-1.0f), sy2 = 0.5f*(h2f-1.0f);
    float sx1 = 0.5f*(w1f-1.0f), sy1 = 0.5f*(h1f-1.0f);

    float cx2[4], cy2[4], cxx2[4], cyy2[4];
    #pragma unroll
    for(int j=0;j<4;j++){
        cx2[j] = (c2v[j].x+1.f)*sx2; cy2[j] = (c2v[j].y+1.f)*sy2;
        cxx2[j] = c2v[j].x*c2v[j].x; cyy2[j] = c2v[j].y*c2v[j].y;
    }
    float colA[4][5] = {};
    #pragma unroll
    for(int i=0;i<2;i++){
        #pragma unroll
        for(int r=0;r<4;r++){
            float2 c1 = c1v[i*4+r];
            float cx1=(c1.x+1.f)*sx1, cy1=(c1.y+1.f)*sy1;
            float cxx1=c1.x*c1.x, cyy1=c1.y*c1.y;
            float rs=0.f, rax=0.f, ray=0.f, raxx=0.f, rayy=0.f;
            #pragma unroll
            for(int j=0;j<4;j++){
                float wgt = exp2f(fmaf(TL2E, acc[i][j][r], -TL2E));
                rs += wgt;
                rax  = fmaf(wgt, cx2[j],  rax);
                ray  = fmaf(wgt, cy2[j],  ray);
                raxx = fmaf(wgt, cxx2[j], raxx);
                rayy = fmaf(wgt, cyy2[j], rayy);
                colA[j][0] += wgt;
                colA[j][1] = fmaf(wgt, cx1,  colA[j][1]);
                colA[j][2] = fmaf(wgt, cy1,  colA[j][2]);
                colA[j][3] = fmaf(wgt, cxx1, colA[j][3]);
                colA[j][4] = fmaf(wgt, cyy1, colA[j][4]);
            }
            rs   = red16_add(rs);
            rax  = red16_add(rax);
            ray  = red16_add(ray);
            raxx = red16_add(raxx);
            rayy = red16_add(rayy);
            if(lr==0){
                int nl = wr*32 + i*16 + lh*4 + r;
                float* rp = parts + ((size_t)wc*128 + nl)*8;
                *(float4*)rp = make_float4(rs, rax, ray, raxx);
                rp[4] = rayy;
            }
        }
    }
    #pragma unroll
    for(int j=0;j<4;j++){
        int ml = j*16 + lr;
        float* cp = parts + COLOFF + (((size_t)wid*4 + lh)*64 + ml)*6;
        *(float2*)cp     = make_float2(colA[j][0], colA[j][1]);
        *(float2*)(cp+2) = make_float2(colA[j][2], colA[j][3]);
        cp[4] = colA[j][4];
    }
    __syncthreads();

    if(tid < 128){
        int p = tid;
        float4 r0 = *(float4*)(parts + ((size_t)0*128 + p)*8);
        float  e0 = parts[((size_t)0*128 + p)*8 + 4];
        float4 r1 = *(float4*)(parts + ((size_t)1*128 + p)*8);
        float  e1 = parts[((size_t)1*128 + p)*8 + 4];
        float* o = wsP + ((size_t)b*NN + n0 + p)*PSTRIDE + mt*5;
        o[0] = r0.x + r1.x;
        o[1] = r0.y + r1.y;
        o[2] = r0.z + r1.z;
        o[3] = r0.w + r1.w;
        o[4] = e0 + e1;
    } else if(tid < 256){
        int p = tid - 128;
        int wcsel = p >> 6, pp = p & 63;
        float s0=0.f,s1=0.f,s2=0.f,s3=0.f,s4=0.f;
        #pragma unroll
        for(int wrv=0; wrv<4; ++wrv){
            #pragma unroll
            for(int lh2=0; lh2<4; ++lh2){
                const float* cp = parts + COLOFF + (((size_t)(wrv*2+wcsel)*4 + lh2)*64 + pp)*6;
                float2 a = *(const float2*)cp;
                float2 q = *(const float2*)(cp+2);
                s0 += a.x; s1 += a.y; s2 += q.x; s3 += q.y; s4 += cp[4];
            }
        }
        float* o = wsP + ((size_t)(BB*NN) + (size_t)b*NN + m0 + p)*PSTRIDE + nt*5;
        o[0]=s0; o[1]=s1; o[2]=s2; o[3]=s3; o[4]=s4;
    }
}

// Window refinement + finalize. Phase 1 via f16 MFMA: query = A row 0, 120 window
// pixels = B rows; D row 0 -> dl[]. Phase 2 softmax unchanged.
__global__ __launch_bounds__(256) void k_win2(
        const __hip_bfloat16* __restrict__ f1b, const __hip_bfloat16* __restrict__ f2b,
        const hf* __restrict__ xf1t, const hf* __restrict__ xf2t,
        const float* __restrict__ wsP,
        float* __restrict__ o_g1, float* __restrict__ o_g1n, float* __restrict__ o_std1,
        float* __restrict__ o_g2, float* __restrict__ o_g2n, float* __restrict__ o_std2,
        float* __restrict__ o_w1, float* __restrict__ o_wstd1,
        float* __restrict__ o_w2, float* __restrict__ o_wstd2,
        float* __restrict__ o_valid,
        const int* __restrict__ h1I, const int* __restrict__ w1I,
        const int* __restrict__ h2I, const int* __restrict__ w2I){
    int gid = blockIdx.x;
    int dir = gid / (BB*NN);
    int bn  = gid % (BB*NN);
    int b   = bn / NN;
    const int* hI            = dir ? h1I  : h2I;
    const int* wI            = dir ? w1I  : w2I;
    float* outW              = dir ? o_w2 : o_w1;
    float* outStd            = dir ? o_wstd2 : o_wstd1;
    float* oG                = dir ? o_g2  : o_g1;
    float* oGn               = dir ? o_g2n : o_g1n;
    float* oSd               = dir ? o_std2: o_std1;

    int tid = threadIdx.x;
    int lane = tid & 63, wid = tid >> 6;
    int lr = lane & 15, lh = lane >> 4;

    __shared__ __align__(16) unsigned char BA[(128+16)*ROWB];   // B rows 0..127, A rows 128..143
    unsigned char* Bl = BA;
    unsigned char* Al = BA + 128*ROWB;
    __shared__ float dl[128];
    __shared__ float acc5[5][25];

    // ---- finalize this point's g/gn/std from tile partials (absorbed k_red) ----
    {
        const float* basep = wsP + ((size_t)dir*(BB*NN) + bn)*PSTRIDE;
        if(tid < NTILE*5){
            int mtc = tid/5, c = tid - mtc*5;
            acc5[c][mtc] = basep[tid];
        }
    }
    __syncthreads();
    if(tid < 5){
        float s = 0.f;
        #pragma unroll
        for(int m=0;m<NTILE;m++) s += acc5[tid][m];
        acc5[tid][24] = s;
    }
    __syncthreads();
    float S = acc5[0][24], AX = acc5[1][24], AY = acc5[2][24];
    float AXX = acc5[3][24], AYY = acc5[4][24];
    float hfv = (float)hI[0], wfv = (float)wI[0];
    float gdx = AX/S, gdy = AY/S;
    float gx = gdx*(2.0f/(wfv-1.0f)) - 1.0f;
    float gy = gdy*(2.0f/(hfv-1.0f)) - 1.0f;
    if(tid == 0){
        float vx0 = AXX/S - gx*gx, vy0 = AYY/S - gy*gy;
        float sd0 = sqrtf(fmaxf(vx0,1e-6f)) + sqrtf(fmaxf(vy0,1e-6f));
        oG[(size_t)bn*2+0]=gdx; oG[(size_t)bn*2+1]=gdy;
        oGn[(size_t)bn*2+0]=gx; oGn[(size_t)bn*2+1]=gy;
        oSd[bn]=sd0;
        o_valid[gid]=1.0f;
    }

    int xb, yb;
    {   int t1; float tw;
        bsetup(gx - 0.125f, WW, xb, t1, tw);
        bsetup(gy - 0.125f, HH, yb, t1, tw);
    }

    // ---- stage A (query row 0, bf16 -> f16) and B (128 window rows, clamped) ----
    {
        const __hip_bfloat16* fQ = (dir ? f2b : f1b) + (size_t)bn*CC;
        if(tid < 16){
            const uint* qsrc = (const uint*)fQ + tid*4;   // 8 bf16
            h8 hv;
            #pragma unroll
            for(int d=0; d<4; ++d){
                uint u = qsrc[d];
                hv[2*d+0] = (hf)__uint_as_float(u << 16);
                hv[2*d+1] = (hf)__uint_as_float(u & 0xffff0000u);
            }
            *(h8*)(Al + tid*16) = hv;
        }
        const hf* mapT = (dir ? xf1t : xf2t) + (size_t)b*HW*CC;
        #pragma unroll
        for(int it=0; it<8; ++it){
            int idx = tid + it*256;            // 128 rows x 16 chunks of 16B
            int row = idx >> 4, ch = idx & 15;
            int pc = row < XN*YN ? row : (XN*YN-1);
            int ky = pc / XN, kx = pc - ky*XN;
            int py = yb + ky; if(py > HH-1) py = HH-1;
            int px = xb + kx; if(px > WW-1) px = WW-1;
            *(uint4*)(Bl + row*ROWB + ch*16) =
                *(const uint4*)((const unsigned char*)(mapT + ((size_t)(py*WW + px))*CC) + ch*16);
        }
    }
    __syncthreads();
    {
        h8 afr[4];
        #pragma unroll
        for(int kk=0; kk<4; ++kk)
            afr[kk] = *(const h8*)(Al + lr*ROWB + lh*16 + kk*64);
        #pragma unroll
        for(int tt=0; tt<2; ++tt){
            int tile = wid + tt*4;
            f32x4 acc = {};
            #pragma unroll
            for(int kk=0; kk<4; ++kk){
                h8 bfr = *(const h8*)(Bl + (tile*16 + lr)*ROWB + lh*16 + kk*64);
                acc = __builtin_amdgcn_mfma_f32_16x16x32_f16(afr[kk], bfr, acc, 0,0,0);
            }
            if(lane < 16) dl[tile*16 + lane] = acc[0];   // D row 0: col=lane&15, reg 0
        }
    }
    __syncthreads();

    // ---- phase 2: bilinear-combine -> softmax -> moments ----
    float logit = -INFINITY, wcx = 0.f, wcy = 0.f;
    if(tid < SS){
        int i = tid % 9, j = tid / 9;
        wcx = gx + (-0.125f + 0.03125f*(float)i);
        wcy = gy + (-0.125f + 0.03125f*(float)j);
        int x0,x1,y0,y1; float wx,wy;
        bsetup(wcx, WW, x0,x1,wx);
        bsetup(wcy, HH, y0,y1,wy);
        int r0 = (y0-yb)*XN - xb, r1 = (y1-yb)*XN - xb;
        float d00=dl[r0+x0], d01=dl[r0+x1], d10=dl[r1+x0], d11=dl[r1+x1];
        logit = d00*(1.f-wx)*(1.f-wy) + d01*wx*(1.f-wy) + d10*(1.f-wx)*wy + d11*wx*wy;
    }

    float M = red64_max(logit);
    __shared__ float mred[4];
    if(lane==0) mred[wid] = M;
    __syncthreads();
    M = fmaxf(fmaxf(mred[0],mred[1]), fmaxf(mred[2],mred[3]));

    float w = (tid < SS) ? __expf(logit - M) : 0.f;
    float v0 = red64_add(w);
    float v1 = red64_add(w*wcx);
    float v2 = red64_add(w*wcy);
    float v3 = red64_add(w*wcx*wcx);
    float v4 = red64_add(w*wcy*wcy);
    __shared__ float sred[4][5];
    if(lane==0){ sred[wid][0]=v0; sred[wid][1]=v1; sred[wid][2]=v2; sred[wid][3]=v3; sred[wid][4]=v4; }
    __syncthreads();
    if(tid==0){
        float Sw = sred[0][0]+sred[1][0]+sred[2][0]+sred[3][0];
        float ex = (sred[0][1]+sred[1][1]+sred[2][1]+sred[3][1])/Sw;
        float ey = (sred[0][2]+sred[1][2]+sred[2][2]+sred[3][2])/Sw;
        float vx = (sred[0][3]+sred[1][3]+sred[2][3]+sred[3][3])/Sw - ex*ex;
        float vy = (sred[0][4]+sred[1][4]+sred[2][4]+sred[3][4])/Sw - ey*ey;
        float sd = sqrtf(fmaxf(vx,1e-6f)) + sqrtf(fmaxf(vy,1e-6f));
        outW[(size_t)bn*2+0] = (ex+1.0f)*0.5f*(wfv-1.0f);
        outW[(size_t)bn*2+1] = (ey+1.0f)*0.5f*(hfv-1.0f);
        outStd[bn] = sd;
    }
}

extern "C" void kernel_launch(void* const* d_in, const int* in_sizes, int n_in,
                              void* d_out, int out_size, void* d_ws, size_t ws_size,
                              hipStream_t stream){
    const float* xf1 = (const float*)d_in[0];
    const float* xf2 = (const float*)d_in[1];
    const float* c1n = (const float*)d_in[2];
    const float* c2n = (const float*)d_in[3];
    const int* h1 = (const int*)d_in[4];
    const int* w1 = (const int*)d_in[5];
    const int* h2 = (const int*)d_in[6];
    const int* w2 = (const int*)d_in[7];
    float* out = (float*)d_out;

    hf* xf1r = (hf*)d_ws;                               // B*HW*C f16 raw transposed
    hf* xf2r = xf1r + (size_t)BB*HW*CC;
    hf* xf1t = xf2r + (size_t)BB*HW*CC;                 // B*HW*C f16 T*normalized
    hf* xf2t = xf1t + (size_t)BB*HW*CC;
    __hip_bfloat16* f1b = (__hip_bfloat16*)(xf2t + (size_t)BB*HW*CC);   // B*N*C bf16
    __hip_bfloat16* f2b = f1b + (size_t)BB*NN*CC;
    float* wsP = (float*)(f2b + (size_t)BB*NN*CC);      // [2][BB*NN][PSTRIDE] f32

    float* o_coord1 = out + 0;
    float* o_coord2 = out + 12288;
    float* o_g1     = out + 24576;
    float* o_g2     = out + 36864;
    float* o_w1     = out + 49152;
    float* o_w2     = out + 61440;
    float* o_g1n    = out + 73728;
    float* o_g2n    = out + 86016;
    float* o_std1   = out + 98304;
    float* o_std2   = out + 104448;
    float* o_wstd1  = out + 110592;
    float* o_wstd2  = out + 116736;
    float* o_valid  = out + 122880;

    hipLaunchKernelGGL(k_normT, dim3(2*BB*(HW/32)), dim3(256), 0, stream,
                       xf1, xf2, xf1r, xf2r, xf1t, xf2t);
    hipLaunchKernelGGL(k_feats, dim3(2*BB*NN/4), dim3(256), 0, stream,
                       xf1r, xf2r, c1n, c2n, f1b, f2b, o_coord1, o_coord2, h1, w1, h2, w2);
    hipLaunchKernelGGL(k_corr, dim3(BB*NTILE*NTILE), dim3(512), 0, stream,
                       f1b, f2b, c1n, c2n, wsP, h1, w1, h2, w2);
    hipLaunchKernelGGL(k_win2, dim3(2*BB*NN), dim3(256), 0, stream,
                       f1b, f2b, xf1t, xf2t, wsP,
                       o_g1, o_g1n, o_std1, o_g2, o_g2n, o_std2,
                       o_w1, o_wstd1, o_w2, o_wstd2, o_valid, h1, w1, h2, w2);
}

// Round 13
// 87.608 us; speedup vs baseline: 1.0010x; 1.0010x over previous
//
#include <hip/hip_runtime.h>
#include <hip/hip_bf16.h>
#include <math.h>

#define BB 2
#define CC 128
#define HH 60
#define WW 80
#define NN 3072
#define TT 16.0f
#define SS 81
#define HW (HH*WW)
#define NTILE 24   // 3072/128
#define LDA 136    // 128 + 8 bf16 pad (k_corr tiles)
#define XN 12
#define YN 10
#define PSTRIDE 128   // floats per point in ws (120 used)
#define ROWB 256      // 128 f16 per window row, linear; XOR-swizzled access

typedef __attribute__((ext_vector_type(8))) short short8;
typedef __attribute__((ext_vector_type(4))) float f32x4;
typedef _Float16 hf;
typedef _Float16 __attribute__((ext_vector_type(2))) h2;
typedef _Float16 __attribute__((ext_vector_type(8))) h8;

// LDS bank swizzle for row-major [row][256B] tiles read column-wise (G4/m214).
__device__ __forceinline__ int swz(int row, int byteoff){
    return byteoff ^ ((row & 7) << 4);
}

// DPP cross-lane terms (VALU pipe, no DS). dpp_ctrl must be a literal -> template.
template<int CTRL>
__device__ __forceinline__ float dppterm(float s){
    return __int_as_float(__builtin_amdgcn_update_dpp(0, __float_as_int(s), CTRL, 0xf, 0xf, true));
}
__device__ __forceinline__ float red8_add(float s){
    s += dppterm<0xB1>(s); s += dppterm<0x4E>(s); s += dppterm<0x141>(s); return s;
}
__device__ __forceinline__ float red16_add(float s){
    s += dppterm<0xB1>(s); s += dppterm<0x4E>(s); s += dppterm<0x141>(s); s += dppterm<0x140>(s); return s;
}
__device__ __forceinline__ float swz16_add(float s){
    return s + __int_as_float(__builtin_amdgcn_ds_swizzle(__float_as_int(s), 0x401F));
}
__device__ __forceinline__ float red64_add(float s){
    s = red16_add(s); s = swz16_add(s); s += __shfl_xor(s, 32); return s;
}
__device__ __forceinline__ float red64_max(float s){
    s = fmaxf(s, dppterm<0xB1>(s)); s = fmaxf(s, dppterm<0x4E>(s));
    s = fmaxf(s, dppterm<0x141>(s)); s = fmaxf(s, dppterm<0x140>(s));
    s = fmaxf(s, __int_as_float(__builtin_amdgcn_ds_swizzle(__float_as_int(s), 0x401F)));
    s = fmaxf(s, __shfl_xor(s, 32));
    return s;
}

__device__ __forceinline__ void bsetup(float cn, int L, int& i0, int& i1, float& w){
    float x = (cn + 1.0f) * 0.5f * (float)(L - 1);
    float x0 = floorf(x);
    w = x - x0;
    int xi = (int)x0;
    i0 = xi < 0 ? 0 : (xi > L - 1 ? L - 1 : xi);
    i1 = (i0 + 1 > L - 1) ? L - 1 : (i0 + 1);
}

// Transpose + per-pixel L2 stats -> f16 raw map + f16 T*normalized map.
__global__ __launch_bounds__(256) void k_normT(
        const float* __restrict__ xf1, const float* __restrict__ xf2,
        hf* __restrict__ xf1r, hf* __restrict__ xf2r,
        hf* __restrict__ xf1t, hf* __restrict__ xf2t){
    int idx = blockIdx.x;
    int map = idx / (BB*(HW/32));
    int rem = idx % (BB*(HW/32));
    int b   = rem / (HW/32);
    int hw0 = (rem % (HW/32)) * 32;
    const float* src = (map ? xf2 : xf1) + (size_t)b*CC*HW + hw0;
    hf* dstR = (map ? xf2r : xf1r) + ((size_t)(b*HW + hw0))*CC;
    hf* dstT = (map ? xf2t : xf1t) + ((size_t)(b*HW + hw0))*CC;

    __shared__ float tile[CC][33];
    int tid = threadIdx.x;
    {
        int p = tid & 31, c0 = tid >> 5;
        #pragma unroll
        for(int i=0;i<16;i++){
            int c = i*8 + c0;
            tile[c][p] = src[(size_t)c*HW + p];
        }
    }
    __syncthreads();
    int q = tid >> 3, l = tid & 7;
    float v[16];
    float ss = 0.f;
    #pragma unroll
    for(int k=0;k<16;k++){ v[k] = tile[l*16+k][q]; ss += v[k]*v[k]; }
    ss = red8_add(ss);
    float inv = 1.0f / sqrtf(ss + 1e-12f);
    float tsc = TT * inv;
    union { hf h[16]; uint4 u[2]; } R, T;
    #pragma unroll
    for(int k=0;k<16;k++){ R.h[k] = (hf)v[k]; T.h[k] = (hf)(v[k]*tsc); }
    uint4* oR = (uint4*)(dstR + (size_t)q*CC + l*16);
    uint4* oT = (uint4*)(dstT + (size_t)q*CC + l*16);
    oR[0] = R.u[0]; oR[1] = R.u[1];
    oT[0] = T.u[0]; oT[1] = T.u[1];
}

// Bilinear sample RAW transposed f16 map, L2-normalize -> bf16 features + denormed
// coords. 4 independent wave-queries per 256-thread block.
__global__ __launch_bounds__(256) void k_feats(
        const hf* __restrict__ xf1r, const hf* __restrict__ xf2r,
        const float* __restrict__ c1n, const float* __restrict__ c2n,
        __hip_bfloat16* __restrict__ f1b, __hip_bfloat16* __restrict__ f2b,
        float* __restrict__ o_coord1, float* __restrict__ o_coord2,
        const int* __restrict__ h1I, const int* __restrict__ w1I,
        const int* __restrict__ h2I, const int* __restrict__ w2I){
    int tid = threadIdx.x;
    int gid = blockIdx.x*4 + (tid >> 6);
    int dir = gid / (BB*NN);
    int bn  = gid % (BB*NN);
    int b = bn / NN;
    const hf* raw = dir ? xf2r : xf1r;
    const float* cn = dir ? c2n : c1n;
    __hip_bfloat16* fOutB = dir ? f2b : f1b;
    float* coordOut = dir ? o_coord2 : o_coord1;
    const int* hI = dir ? h2I : h1I;
    const int* wI = dir ? w2I : w1I;

    int t = tid & 63;   // channels 2t,2t+1
    float cnx = cn[(size_t)bn*2+0], cny = cn[(size_t)bn*2+1];
    int x0,x1,y0,y1; float wx,wy;
    bsetup(cnx, WW, x0,x1,wx);
    bsetup(cny, HH, y0,y1,wy);
    const hf* base = raw + (size_t)(b*HW)*CC;
    const uint* r00 = (const uint*)(base + (size_t)(y0*WW+x0)*CC) + t;
    const uint* r01 = (const uint*)(base + (size_t)(y0*WW+x1)*CC) + t;
    const uint* r10 = (const uint*)(base + (size_t)(y1*WW+x0)*CC) + t;
    const uint* r11 = (const uint*)(base + (size_t)(y1*WW+x1)*CC) + t;
    union { uint u; h2 v; } u00, u01, u10, u11;
    u00.u = *r00; u01.u = *r01; u10.u = *r10; u11.u = *r11;
    float w00=(1.f-wx)*(1.f-wy), w01=wx*(1.f-wy), w10=(1.f-wx)*wy, w11=wx*wy;
    float fx = w00*(float)u00.v.x + w01*(float)u01.v.x + w10*(float)u10.v.x + w11*(float)u11.v.x;
    float fy = w00*(float)u00.v.y + w01*(float)u01.v.y + w10*(float)u10.v.y + w11*(float)u11.v.y;
    float ss = fx*fx + fy*fy;
    ss = red64_add(ss);
    float inv = 1.0f / sqrtf(ss + 1e-12f);
    unsigned short blo = __bfloat16_as_ushort(__float2bfloat16(fx*inv));
    unsigned short bhi = __bfloat16_as_ushort(__float2bfloat16(fy*inv));
    ((uint*)(fOutB + (size_t)bn*CC))[t] = ((uint)bhi << 16) | blo;
    if(t==0){
        float h=(float)hI[0], w=(float)wI[0];
        coordOut[(size_t)bn*2+0] = (cnx+1.0f)*0.5f*(w-1.0f);
        coordOut[(size_t)bn*2+1] = (cny+1.0f)*0.5f*(h-1.0f);
    }
}

// Fused correlation v5 (unchanged).
__global__ __launch_bounds__(512,4) void k_corr(
        const __hip_bfloat16* __restrict__ f1b, const __hip_bfloat16* __restrict__ f2b,
        const float* __restrict__ c1n, const float* __restrict__ c2n,
        float* __restrict__ wsP,
        const int* __restrict__ h1I, const int* __restrict__ w1I,
        const int* __restrict__ h2I, const int* __restrict__ w2I){
    const int nwg = BB*NTILE*NTILE;
    int blk = blockIdx.x;
    blk = (blk & 7)*(nwg/8) + (blk >> 3);
    int b   = blk / (NTILE*NTILE);
    int rem = blk % (NTILE*NTILE);
    int nt = rem / NTILE, mt = rem % NTILE;
    int n0 = nt*128, m0 = mt*128;
    int tid = threadIdx.x;
    int lane = tid & 63, wid = tid >> 6;
    int wr = wid >> 1, wc = wid & 1;
    int lr = lane & 15, lh = lane >> 4;

    __shared__ __align__(16) unsigned short smem[2*128*LDA];
    unsigned short* As = smem;
    unsigned short* Bs = smem + 128*LDA;
    float* parts = (float*)smem;
    const int COLOFF = 2*128*8;

    {
        const unsigned short* gA = (const unsigned short*)f1b + ((size_t)b*NN + n0)*CC;
        const unsigned short* gB = (const unsigned short*)f2b + ((size_t)b*NN + m0)*CC;
        #pragma unroll
        for(int it=0; it<4; ++it){
            int idx = tid + it*512;
            int r = idx >> 4, q = idx & 15;
            *(uint4*)(As + r*LDA + q*8) = *(const uint4*)(gA + r*CC + q*8);
            *(uint4*)(Bs + r*LDA + q*8) = *(const uint4*)(gB + r*CC + q*8);
        }
    }

    float2 c2v[4], c1v[8];
    #pragma unroll
    for(int j=0;j<4;j++)
        c2v[j] = ((const float2*)c2n)[(size_t)b*NN + m0 + wc*64 + j*16 + lr];
    #pragma unroll
    for(int i=0;i<2;i++)
        #pragma unroll
        for(int r=0;r<4;r++)
            c1v[i*4+r] = ((const float2*)c1n)[(size_t)b*NN + n0 + wr*32 + i*16 + lh*4 + r];

    __syncthreads();

    f32x4 acc[2][4] = {};
    const unsigned short* aBase = As + (wr*32 + lr)*LDA + lh*8;
    const unsigned short* bBase = Bs + (wc*64 + lr)*LDA + lh*8;
    #pragma unroll
    for(int ks=0; ks<4; ++ks){
        short8 afr[2], bfr[4];
        #pragma unroll
        for(int i=0;i<2;i++) afr[i] = *(const short8*)(aBase + i*16*LDA + ks*32);
        #pragma unroll
        for(int j=0;j<4;j++) bfr[j] = *(const short8*)(bBase + j*16*LDA + ks*32);
        #pragma unroll
        for(int i=0;i<2;i++)
            #pragma unroll
            for(int j=0;j<4;j++)
                acc[i][j] = __builtin_amdgcn_mfma_f32_16x16x32_bf16(afr[i], bfr[j], acc[i][j], 0,0,0);
    }
    __syncthreads();

    const float TL2E = 23.08312035f;
    float h1f=(float)h1I[0], w1f=(float)w1I[0], h2f=(float)h2I[0], w2f=(float)w2I[0];
    float sx2 = 0.5f*(w2f-1.0f), sy2 = 0.5f*(h2f-1.0f);
    float sx1 = 0.5f*(w1f-1.0f), sy1 = 0.5f*(h1f-1.0f);

    float cx2[4], cy2[4], cxx2[4], cyy2[4];
    #pragma unroll
    for(int j=0;j<4;j++){
        cx2[j] = (c2v[j].x+1.f)*sx2; cy2[j] = (c2v[j].y+1.f)*sy2;
        cxx2[j] = c2v[j].x*c2v[j].x; cyy2[j] = c2v[j].y*c2v[j].y;
    }
    float colA[4][5] = {};
    #pragma unroll
    for(int i=0;i<2;i++){
        #pragma unroll
        for(int r=0;r<4;r++){
            float2 c1 = c1v[i*4+r];
            float cx1=(c1.x+1.f)*sx1, cy1=(c1.y+1.f)*sy1;
            float cxx1=c1.x*c1.x, cyy1=c1.y*c1.y;
            float rs=0.f, rax=0.f, ray=0.f, raxx=0.f, rayy=0.f;
            #pragma unroll
            for(int j=0;j<4;j++){
                float wgt = exp2f(fmaf(TL2E, acc[i][j][r], -TL2E));
                rs += wgt;
                rax  = fmaf(wgt, cx2[j],  rax);
                ray  = fmaf(wgt, cy2[j],  ray);
                raxx = fmaf(wgt, cxx2[j], raxx);
                rayy = fmaf(wgt, cyy2[j], rayy);
                colA[j][0] += wgt;
                colA[j][1] = fmaf(wgt, cx1,  colA[j][1]);
                colA[j][2] = fmaf(wgt, cy1,  colA[j][2]);
                colA[j][3] = fmaf(wgt, cxx1, colA[j][3]);
                colA[j][4] = fmaf(wgt, cyy1, colA[j][4]);
            }
            rs   = red16_add(rs);
            rax  = red16_add(rax);
            ray  = red16_add(ray);
            raxx = red16_add(raxx);
            rayy = red16_add(rayy);
            if(lr==0){
                int nl = wr*32 + i*16 + lh*4 + r;
                float* rp = parts + ((size_t)wc*128 + nl)*8;
                *(float4*)rp = make_float4(rs, rax, ray, raxx);
                rp[4] = rayy;
            }
        }
    }
    #pragma unroll
    for(int j=0;j<4;j++){
        int ml = j*16 + lr;
        float* cp = parts + COLOFF + (((size_t)wid*4 + lh)*64 + ml)*6;
        *(float2*)cp     = make_float2(colA[j][0], colA[j][1]);
        *(float2*)(cp+2) = make_float2(colA[j][2], colA[j][3]);
        cp[4] = colA[j][4];
    }
    __syncthreads();

    if(tid < 128){
        int p = tid;
        float4 r0 = *(float4*)(parts + ((size_t)0*128 + p)*8);
        float  e0 = parts[((size_t)0*128 + p)*8 + 4];
        float4 r1 = *(float4*)(parts + ((size_t)1*128 + p)*8);
        float  e1 = parts[((size_t)1*128 + p)*8 + 4];
        float* o = wsP + ((size_t)b*NN + n0 + p)*PSTRIDE + mt*5;
        o[0] = r0.x + r1.x;
        o[1] = r0.y + r1.y;
        o[2] = r0.z + r1.z;
        o[3] = r0.w + r1.w;
        o[4] = e0 + e1;
    } else if(tid < 256){
        int p = tid - 128;
        int wcsel = p >> 6, pp = p & 63;
        float s0=0.f,s1=0.f,s2=0.f,s3=0.f,s4=0.f;
        #pragma unroll
        for(int wrv=0; wrv<4; ++wrv){
            #pragma unroll
            for(int lh2=0; lh2<4; ++lh2){
                const float* cp = parts + COLOFF + (((size_t)(wrv*2+wcsel)*4 + lh2)*64 + pp)*6;
                float2 a = *(const float2*)cp;
                float2 q = *(const float2*)(cp+2);
                s0 += a.x; s1 += a.y; s2 += q.x; s3 += q.y; s4 += cp[4];
            }
        }
        float* o = wsP + ((size_t)(BB*NN) + (size_t)b*NN + m0 + p)*PSTRIDE + nt*5;
        o[0]=s0; o[1]=s1; o[2]=s2; o[3]=s3; o[4]=s4;
    }
}

// Window refinement + finalize. Phase 1 via f16 MFMA with XOR-swizzled LDS rows
// (bank-conflict-free): query = A row 0, 120 window pixels = B rows; D row 0 -> dl[].
__global__ __launch_bounds__(256) void k_win2(
        const __hip_bfloat16* __restrict__ f1b, const __hip_bfloat16* __restrict__ f2b,
        const hf* __restrict__ xf1t, const hf* __restrict__ xf2t,
        const float* __restrict__ wsP,
        float* __restrict__ o_g1, float* __restrict__ o_g1n, float* __restrict__ o_std1,
        float* __restrict__ o_g2, float* __restrict__ o_g2n, float* __restrict__ o_std2,
        float* __restrict__ o_w1, float* __restrict__ o_wstd1,
        float* __restrict__ o_w2, float* __restrict__ o_wstd2,
        float* __restrict__ o_valid,
        const int* __restrict__ h1I, const int* __restrict__ w1I,
        const int* __restrict__ h2I, const int* __restrict__ w2I){
    int gid = blockIdx.x;
    int dir = gid / (BB*NN);
    int bn  = gid % (BB*NN);
    int b   = bn / NN;
    const int* hI            = dir ? h1I  : h2I;
    const int* wI            = dir ? w1I  : w2I;
    float* outW              = dir ? o_w2 : o_w1;
    float* outStd            = dir ? o_wstd2 : o_wstd1;
    float* oG                = dir ? o_g2  : o_g1;
    float* oGn               = dir ? o_g2n : o_g1n;
    float* oSd               = dir ? o_std2: o_std1;

    int tid = threadIdx.x;
    int lane = tid & 63, wid = tid >> 6;
    int lr = lane & 15, lh = lane >> 4;

    __shared__ __align__(16) unsigned char BA[(128+16)*ROWB];   // B rows 0..127, A rows 128..143
    unsigned char* Bl = BA;
    unsigned char* Al = BA + 128*ROWB;
    __shared__ float dl[128];
    __shared__ float acc5[5][25];

    // ---- finalize this point's g/gn/std from tile partials (absorbed k_red) ----
    {
        const float* basep = wsP + ((size_t)dir*(BB*NN) + bn)*PSTRIDE;
        if(tid < NTILE*5){
            int mtc = tid/5, c = tid - mtc*5;
            acc5[c][mtc] = basep[tid];
        }
    }
    __syncthreads();
    if(tid < 5){
        float s = 0.f;
        #pragma unroll
        for(int m=0;m<NTILE;m++) s += acc5[tid][m];
        acc5[tid][24] = s;
    }
    __syncthreads();
    float S = acc5[0][24], AX = acc5[1][24], AY = acc5[2][24];
    float AXX = acc5[3][24], AYY = acc5[4][24];
    float hfv = (float)hI[0], wfv = (float)wI[0];
    float gdx = AX/S, gdy = AY/S;
    float gx = gdx*(2.0f/(wfv-1.0f)) - 1.0f;
    float gy = gdy*(2.0f/(hfv-1.0f)) - 1.0f;
    if(tid == 0){
        float vx0 = AXX/S - gx*gx, vy0 = AYY/S - gy*gy;
        float sd0 = sqrtf(fmaxf(vx0,1e-6f)) + sqrtf(fmaxf(vy0,1e-6f));
        oG[(size_t)bn*2+0]=gdx; oG[(size_t)bn*2+1]=gdy;
        oGn[(size_t)bn*2+0]=gx; oGn[(size_t)bn*2+1]=gy;
        oSd[bn]=sd0;
        o_valid[gid]=1.0f;
    }

    int xb, yb;
    {   int t1; float tw;
        bsetup(gx - 0.125f, WW, xb, t1, tw);
        bsetup(gy - 0.125f, HH, yb, t1, tw);
    }

    // ---- stage A (query row 0; row-0 swizzle = identity) and B (128 rows, swizzled) ----
    {
        const __hip_bfloat16* fQ = (dir ? f2b : f1b) + (size_t)bn*CC;
        if(tid < 16){
            const uint* qsrc = (const uint*)fQ + tid*4;   // 8 bf16
            h8 hv;
            #pragma unroll
            for(int d=0; d<4; ++d){
                uint u = qsrc[d];
                hv[2*d+0] = (hf)__uint_as_float(u << 16);
                hv[2*d+1] = (hf)__uint_as_float(u & 0xffff0000u);
            }
            *(h8*)(Al + tid*16) = hv;
        }
        const hf* mapT = (dir ? xf1t : xf2t) + (size_t)b*HW*CC;
        #pragma unroll
        for(int it=0; it<8; ++it){
            int idx = tid + it*256;            // 128 rows x 16 chunks of 16B
            int row = idx >> 4, ch = idx & 15;
            int pc = row < XN*YN ? row : (XN*YN-1);
            int ky = pc / XN, kx = pc - ky*XN;
            int py = yb + ky; if(py > HH-1) py = HH-1;
            int px = xb + kx; if(px > WW-1) px = WW-1;
            *(uint4*)(Bl + row*ROWB + swz(row, ch*16)) =
                *(const uint4*)((const unsigned char*)(mapT + ((size_t)(py*WW + px))*CC) + ch*16);
        }
    }
    __syncthreads();
    {
        h8 afr[4];
        #pragma unroll
        for(int kk=0; kk<4; ++kk)
            afr[kk] = *(const h8*)(Al + lr*ROWB + swz(lr, lh*16 + kk*64));
        #pragma unroll
        for(int tt=0; tt<2; ++tt){
            int tile = wid + tt*4;
            f32x4 acc = {};
            #pragma unroll
            for(int kk=0; kk<4; ++kk){
                int brow = tile*16 + lr;
                h8 bfr = *(const h8*)(Bl + brow*ROWB + swz(brow, lh*16 + kk*64));
                acc = __builtin_amdgcn_mfma_f32_16x16x32_f16(afr[kk], bfr, acc, 0,0,0);
            }
            if(lane < 16) dl[tile*16 + lane] = acc[0];   // D row 0: col=lane&15, reg 0
        }
    }
    __syncthreads();

    // ---- phase 2: bilinear-combine -> softmax -> moments ----
    float logit = -INFINITY, wcx = 0.f, wcy = 0.f;
    if(tid < SS){
        int i = tid % 9, j = tid / 9;
        wcx = gx + (-0.125f + 0.03125f*(float)i);
        wcy = gy + (-0.125f + 0.03125f*(float)j);
        int x0,x1,y0,y1; float wx,wy;
        bsetup(wcx, WW, x0,x1,wx);
        bsetup(wcy, HH, y0,y1,wy);
        int r0 = (y0-yb)*XN - xb, r1 = (y1-yb)*XN - xb;
        float d00=dl[r0+x0], d01=dl[r0+x1], d10=dl[r1+x0], d11=dl[r1+x1];
        logit = d00*(1.f-wx)*(1.f-wy) + d01*wx*(1.f-wy) + d10*(1.f-wx)*wy + d11*wx*wy;
    }

    float M = red64_max(logit);
    __shared__ float mred[4];
    if(lane==0) mred[wid] = M;
    __syncthreads();
    M = fmaxf(fmaxf(mred[0],mred[1]), fmaxf(mred[2],mred[3]));

    float w = (tid < SS) ? __expf(logit - M) : 0.f;
    float v0 = red64_add(w);
    float v1 = red64_add(w*wcx);
    float v2 = red64_add(w*wcy);
    float v3 = red64_add(w*wcx*wcx);
    float v4 = red64_add(w*wcy*wcy);
    __shared__ float sred[4][5];
    if(lane==0){ sred[wid][0]=v0; sred[wid][1]=v1; sred[wid][2]=v2; sred[wid][3]=v3; sred[wid][4]=v4; }
    __syncthreads();
    if(tid==0){
        float Sw = sred[0][0]+sred[1][0]+sred[2][0]+sred[3][0];
        float ex = (sred[0][1]+sred[1][1]+sred[2][1]+sred[3][1])/Sw;
        float ey = (sred[0][2]+sred[1][2]+sred[2][2]+sred[3][2])/Sw;
        float vx = (sred[0][3]+sred[1][3]+sred[2][3]+sred[3][3])/Sw - ex*ex;
        float vy = (sred[0][4]+sred[1][4]+sred[2][4]+sred[3][4])/Sw - ey*ey;
        float sd = sqrtf(fmaxf(vx,1e-6f)) + sqrtf(fmaxf(vy,1e-6f));
        outW[(size_t)bn*2+0] = (ex+1.0f)*0.5f*(wfv-1.0f);
        outW[(size_t)bn*2+1] = (ey+1.0f)*0.5f*(hfv-1.0f);
        outStd[bn] = sd;
    }
}

extern "C" void kernel_launch(void* const* d_in, const int* in_sizes, int n_in,
                              void* d_out, int out_size, void* d_ws, size_t ws_size,
                              hipStream_t stream){
    const float* xf1 = (const float*)d_in[0];
    const float* xf2 = (const float*)d_in[1];
    const float* c1n = (const float*)d_in[2];
    const float* c2n = (const float*)d_in[3];
    const int* h1 = (const int*)d_in[4];
    const int* w1 = (const int*)d_in[5];
    const int* h2 = (const int*)d_in[6];
    const int* w2 = (const int*)d_in[7];
    float* out = (float*)d_out;

    hf* xf1r = (hf*)d_ws;                               // B*HW*C f16 raw transposed
    hf* xf2r = xf1r + (size_t)BB*HW*CC;
    hf* xf1t = xf2r + (size_t)BB*HW*CC;                 // B*HW*C f16 T*normalized
    hf* xf2t = xf1t + (size_t)BB*HW*CC;
    __hip_bfloat16* f1b = (__hip_bfloat16*)(xf2t + (size_t)BB*HW*CC);   // B*N*C bf16
    __hip_bfloat16* f2b = f1b + (size_t)BB*NN*CC;
    float* wsP = (float*)(f2b + (size_t)BB*NN*CC);      // [2][BB*NN][PSTRIDE] f32

    float* o_coord1 = out + 0;
    float* o_coord2 = out + 12288;
    float* o_g1     = out + 24576;
    float* o_g2     = out + 36864;
    float* o_w1     = out + 49152;
    float* o_w2     = out + 61440;
    float* o_g1n    = out + 73728;
    float* o_g2n    = out + 86016;
    float* o_std1   = out + 98304;
    float* o_std2   = out + 104448;
    float* o_wstd1  = out + 110592;
    float* o_wstd2  = out + 116736;
    float* o_valid  = out + 122880;

    hipLaunchKernelGGL(k_normT, dim3(2*BB*(HW/32)), dim3(256), 0, stream,
                       xf1, xf2, xf1r, xf2r, xf1t, xf2t);
    hipLaunchKernelGGL(k_feats, dim3(2*BB*NN/4), dim3(256), 0, stream,
                       xf1r, xf2r, c1n, c2n, f1b, f2b, o_coord1, o_coord2, h1, w1, h2, w2);
    hipLaunchKernelGGL(k_corr, dim3(BB*NTILE*NTILE), dim3(512), 0, stream,
                       f1b, f2b, c1n, c2n, wsP, h1, w1, h2, w2);
    hipLaunchKernelGGL(k_win2, dim3(2*BB*NN), dim3(256), 0, stream,
                       f1b, f2b, xf1t, xf2t, wsP,
                       o_g1, o_g1n, o_std1, o_g2, o_g2n, o_std2,
                       o_w1, o_wstd1, o_w2, o_wstd2, o_valid, h1, w1, h2, w2);
}

// Round 14
// 61.559 us; speedup vs baseline: 1.4246x; 1.4232x over previous
//
#include <hip/hip_runtime.h>
#include <hip/hip_bf16.h>
#include <math.h>

#define BB 2
#define CC 128
#define HH 60
#define WW 80
#define NN 3072
#define TT 16.0f
#define SS 81
#define HW (HH*WW)
#define NTILE 24   // 3072/128
#define LDA 136    // 128 + 8 bf16 pad (k_corr tiles)
#define XN 12
#define YN 10
#define PSTRIDE 128   // floats per point in ws (120 used)

typedef __attribute__((ext_vector_type(8))) short short8;
typedef __attribute__((ext_vector_type(4))) float f32x4;
typedef _Float16 hf;
typedef _Float16 __attribute__((ext_vector_type(2))) h2;

#if __has_builtin(__builtin_amdgcn_fdot2)
#define FDOT2(a,b,c) __builtin_amdgcn_fdot2((a),(b),(c),false)
#else
#define FDOT2(a,b,c) ((c) + (float)(a).x*(float)(b).x + (float)(a).y*(float)(b).y)
#endif

// DPP cross-lane terms (VALU pipe, no DS). dpp_ctrl must be a literal -> template.
template<int CTRL>
__device__ __forceinline__ float dppterm(float s){
    return __int_as_float(__builtin_amdgcn_update_dpp(0, __float_as_int(s), CTRL, 0xf, 0xf, true));
}
__device__ __forceinline__ float red8_add(float s){
    s += dppterm<0xB1>(s); s += dppterm<0x4E>(s); s += dppterm<0x141>(s); return s;
}
__device__ __forceinline__ float red16_add(float s){
    s += dppterm<0xB1>(s); s += dppterm<0x4E>(s); s += dppterm<0x141>(s); s += dppterm<0x140>(s); return s;
}
__device__ __forceinline__ float swz16_add(float s){
    return s + __int_as_float(__builtin_amdgcn_ds_swizzle(__float_as_int(s), 0x401F));
}
__device__ __forceinline__ float red64_add(float s){
    s = red16_add(s); s = swz16_add(s); s += __shfl_xor(s, 32); return s;
}
__device__ __forceinline__ float red64_max(float s){
    s = fmaxf(s, dppterm<0xB1>(s)); s = fmaxf(s, dppterm<0x4E>(s));
    s = fmaxf(s, dppterm<0x141>(s)); s = fmaxf(s, dppterm<0x140>(s));
    s = fmaxf(s, __int_as_float(__builtin_amdgcn_ds_swizzle(__float_as_int(s), 0x401F)));
    s = fmaxf(s, __shfl_xor(s, 32));
    return s;
}

__device__ __forceinline__ void bsetup(float cn, int L, int& i0, int& i1, float& w){
    float x = (cn + 1.0f) * 0.5f * (float)(L - 1);
    float x0 = floorf(x);
    w = x - x0;
    int xi = (int)x0;
    i0 = xi < 0 ? 0 : (xi > L - 1 ? L - 1 : xi);
    i1 = (i0 + 1 > L - 1) ? L - 1 : (i0 + 1);
}

// Transpose + per-pixel L2 stats -> f16 raw map + f16 T*normalized map.
__global__ __launch_bounds__(256) void k_normT(
        const float* __restrict__ xf1, const float* __restrict__ xf2,
        hf* __restrict__ xf1r, hf* __restrict__ xf2r,
        hf* __restrict__ xf1t, hf* __restrict__ xf2t){
    int idx = blockIdx.x;
    int map = idx / (BB*(HW/32));
    int rem = idx % (BB*(HW/32));
    int b   = rem / (HW/32);
    int hw0 = (rem % (HW/32)) * 32;
    const float* src = (map ? xf2 : xf1) + (size_t)b*CC*HW + hw0;
    hf* dstR = (map ? xf2r : xf1r) + ((size_t)(b*HW + hw0))*CC;
    hf* dstT = (map ? xf2t : xf1t) + ((size_t)(b*HW + hw0))*CC;

    __shared__ float tile[CC][33];
    int tid = threadIdx.x;
    {
        int p = tid & 31, c0 = tid >> 5;
        #pragma unroll
        for(int i=0;i<16;i++){
            int c = i*8 + c0;
            tile[c][p] = src[(size_t)c*HW + p];
        }
    }
    __syncthreads();
    int q = tid >> 3, l = tid & 7;
    float v[16];
    float ss = 0.f;
    #pragma unroll
    for(int k=0;k<16;k++){ v[k] = tile[l*16+k][q]; ss += v[k]*v[k]; }
    ss = red8_add(ss);
    float inv = 1.0f / sqrtf(ss + 1e-12f);
    float tsc = TT * inv;
    union { hf h[16]; uint4 u[2]; } R, T;
    #pragma unroll
    for(int k=0;k<16;k++){ R.h[k] = (hf)v[k]; T.h[k] = (hf)(v[k]*tsc); }
    uint4* oR = (uint4*)(dstR + (size_t)q*CC + l*16);
    uint4* oT = (uint4*)(dstT + (size_t)q*CC + l*16);
    oR[0] = R.u[0]; oR[1] = R.u[1];
    oT[0] = T.u[0]; oT[1] = T.u[1];
}

// Bilinear sample RAW transposed f16 map, L2-normalize -> bf16 features + denormed
// coords. 4 independent wave-queries per 256-thread block.
__global__ __launch_bounds__(256) void k_feats(
        const hf* __restrict__ xf1r, const hf* __restrict__ xf2r,
        const float* __restrict__ c1n, const float* __restrict__ c2n,
        __hip_bfloat16* __restrict__ f1b, __hip_bfloat16* __restrict__ f2b,
        float* __restrict__ o_coord1, float* __restrict__ o_coord2,
        const int* __restrict__ h1I, const int* __restrict__ w1I,
        const int* __restrict__ h2I, const int* __restrict__ w2I){
    int tid = threadIdx.x;
    int gid = blockIdx.x*4 + (tid >> 6);
    int dir = gid / (BB*NN);
    int bn  = gid % (BB*NN);
    int b = bn / NN;
    const hf* raw = dir ? xf2r : xf1r;
    const float* cn = dir ? c2n : c1n;
    __hip_bfloat16* fOutB = dir ? f2b : f1b;
    float* coordOut = dir ? o_coord2 : o_coord1;
    const int* hI = dir ? h2I : h1I;
    const int* wI = dir ? w2I : w1I;

    int t = tid & 63;   // channels 2t,2t+1
    float cnx = cn[(size_t)bn*2+0], cny = cn[(size_t)bn*2+1];
    int x0,x1,y0,y1; float wx,wy;
    bsetup(cnx, WW, x0,x1,wx);
    bsetup(cny, HH, y0,y1,wy);
    const hf* base = raw + (size_t)(b*HW)*CC;
    const uint* r00 = (const uint*)(base + (size_t)(y0*WW+x0)*CC) + t;
    const uint* r01 = (const uint*)(base + (size_t)(y0*WW+x1)*CC) + t;
    const uint* r10 = (const uint*)(base + (size_t)(y1*WW+x0)*CC) + t;
    const uint* r11 = (const uint*)(base + (size_t)(y1*WW+x1)*CC) + t;
    union { uint u; h2 v; } u00, u01, u10, u11;
    u00.u = *r00; u01.u = *r01; u10.u = *r10; u11.u = *r11;
    float w00=(1.f-wx)*(1.f-wy), w01=wx*(1.f-wy), w10=(1.f-wx)*wy, w11=wx*wy;
    float fx = w00*(float)u00.v.x + w01*(float)u01.v.x + w10*(float)u10.v.x + w11*(float)u11.v.x;
    float fy = w00*(float)u00.v.y + w01*(float)u01.v.y + w10*(float)u10.v.y + w11*(float)u11.v.y;
    float ss = fx*fx + fy*fy;
    ss = red64_add(ss);
    float inv = 1.0f / sqrtf(ss + 1e-12f);
    unsigned short blo = __bfloat16_as_ushort(__float2bfloat16(fx*inv));
    unsigned short bhi = __bfloat16_as_ushort(__float2bfloat16(fy*inv));
    ((uint*)(fOutB + (size_t)bn*CC))[t] = ((uint)bhi << 16) | blo;
    if(t==0){
        float h=(float)hI[0], w=(float)wI[0];
        coordOut[(size_t)bn*2+0] = (cnx+1.0f)*0.5f*(w-1.0f);
        coordOut[(size_t)bn*2+1] = (cny+1.0f)*0.5f*(h-1.0f);
    }
}

// Fused correlation v5 (unchanged from round 10).
__global__ __launch_bounds__(512,4) void k_corr(
        const __hip_bfloat16* __restrict__ f1b, const __hip_bfloat16* __restrict__ f2b,
        const float* __restrict__ c1n, const float* __restrict__ c2n,
        float* __restrict__ wsP,
        const int* __restrict__ h1I, const int* __restrict__ w1I,
        const int* __restrict__ h2I, const int* __restrict__ w2I){
    const int nwg = BB*NTILE*NTILE;
    int blk = blockIdx.x;
    blk = (blk & 7)*(nwg/8) + (blk >> 3);
    int b   = blk / (NTILE*NTILE);
    int rem = blk % (NTILE*NTILE);
    int nt = rem / NTILE, mt = rem % NTILE;
    int n0 = nt*128, m0 = mt*128;
    int tid = threadIdx.x;
    int lane = tid & 63, wid = tid >> 6;
    int wr = wid >> 1, wc = wid & 1;
    int lr = lane & 15, lh = lane >> 4;

    __shared__ __align__(16) unsigned short smem[2*128*LDA];
    unsigned short* As = smem;
    unsigned short* Bs = smem + 128*LDA;
    float* parts = (float*)smem;
    const int COLOFF = 2*128*8;

    {
        const unsigned short* gA = (const unsigned short*)f1b + ((size_t)b*NN + n0)*CC;
        const unsigned short* gB = (const unsigned short*)f2b + ((size_t)b*NN + m0)*CC;
        #pragma unroll
        for(int it=0; it<4; ++it){
            int idx = tid + it*512;
            int r = idx >> 4, q = idx & 15;
            *(uint4*)(As + r*LDA + q*8) = *(const uint4*)(gA + r*CC + q*8);
            *(uint4*)(Bs + r*LDA + q*8) = *(const uint4*)(gB + r*CC + q*8);
        }
    }

    float2 c2v[4], c1v[8];
    #pragma unroll
    for(int j=0;j<4;j++)
        c2v[j] = ((const float2*)c2n)[(size_t)b*NN + m0 + wc*64 + j*16 + lr];
    #pragma unroll
    for(int i=0;i<2;i++)
        #pragma unroll
        for(int r=0;r<4;r++)
            c1v[i*4+r] = ((const float2*)c1n)[(size_t)b*NN + n0 + wr*32 + i*16 + lh*4 + r];

    __syncthreads();

    f32x4 acc[2][4] = {};
    const unsigned short* aBase = As + (wr*32 + lr)*LDA + lh*8;
    const unsigned short* bBase = Bs + (wc*64 + lr)*LDA + lh*8;
    #pragma unroll
    for(int ks=0; ks<4; ++ks){
        short8 afr[2], bfr[4];
        #pragma unroll
        for(int i=0;i<2;i++) afr[i] = *(const short8*)(aBase + i*16*LDA + ks*32);
        #pragma unroll
        for(int j=0;j<4;j++) bfr[j] = *(const short8*)(bBase + j*16*LDA + ks*32);
        #pragma unroll
        for(int i=0;i<2;i++)
            #pragma unroll
            for(int j=0;j<4;j++)
                acc[i][j] = __builtin_amdgcn_mfma_f32_16x16x32_bf16(afr[i], bfr[j], acc[i][j], 0,0,0);
    }
    __syncthreads();

    const float TL2E = 23.08312035f;
    float h1f=(float)h1I[0], w1f=(float)w1I[0], h2f=(float)h2I[0], w2f=(float)w2I[0];
    float sx2 = 0.5f*(w2f-1.0f), sy2 = 0.5f*(h2f-1.0f);
    float sx1 = 0.5f*(w1f-1.0f), sy1 = 0.5f*(h1f-1.0f);

    float cx2[4], cy2[4], cxx2[4], cyy2[4];
    #pragma unroll
    for(int j=0;j<4;j++){
        cx2[j] = (c2v[j].x+1.f)*sx2; cy2[j] = (c2v[j].y+1.f)*sy2;
        cxx2[j] = c2v[j].x*c2v[j].x; cyy2[j] = c2v[j].y*c2v[j].y;
    }
    float colA[4][5] = {};
    #pragma unroll
    for(int i=0;i<2;i++){
        #pragma unroll
        for(int r=0;r<4;r++){
            float2 c1 = c1v[i*4+r];
            float cx1=(c1.x+1.f)*sx1, cy1=(c1.y+1.f)*sy1;
            float cxx1=c1.x*c1.x, cyy1=c1.y*c1.y;
            float rs=0.f, rax=0.f, ray=0.f, raxx=0.f, rayy=0.f;
            #pragma unroll
            for(int j=0;j<4;j++){
                float wgt = exp2f(fmaf(TL2E, acc[i][j][r], -TL2E));
                rs += wgt;
                rax  = fmaf(wgt, cx2[j],  rax);
                ray  = fmaf(wgt, cy2[j],  ray);
                raxx = fmaf(wgt, cxx2[j], raxx);
                rayy = fmaf(wgt, cyy2[j], rayy);
                colA[j][0] += wgt;
                colA[j][1] = fmaf(wgt, cx1,  colA[j][1]);
                colA[j][2] = fmaf(wgt, cy1,  colA[j][2]);
                colA[j][3] = fmaf(wgt, cxx1, colA[j][3]);
                colA[j][4] = fmaf(wgt, cyy1, colA[j][4]);
            }
            rs   = red16_add(rs);
            rax  = red16_add(rax);
            ray  = red16_add(ray);
            raxx = red16_add(raxx);
            rayy = red16_add(rayy);
            if(lr==0){
                int nl = wr*32 + i*16 + lh*4 + r;
                float* rp = parts + ((size_t)wc*128 + nl)*8;
                *(float4*)rp = make_float4(rs, rax, ray, raxx);
                rp[4] = rayy;
            }
        }
    }
    #pragma unroll
    for(int j=0;j<4;j++){
        int ml = j*16 + lr;
        float* cp = parts + COLOFF + (((size_t)wid*4 + lh)*64 + ml)*6;
        *(float2*)cp     = make_float2(colA[j][0], colA[j][1]);
        *(float2*)(cp+2) = make_float2(colA[j][2], colA[j][3]);
        cp[4] = colA[j][4];
    }
    __syncthreads();

    if(tid < 128){
        int p = tid;
        float4 r0 = *(float4*)(parts + ((size_t)0*128 + p)*8);
        float  e0 = parts[((size_t)0*128 + p)*8 + 4];
        float4 r1 = *(float4*)(parts + ((size_t)1*128 + p)*8);
        float  e1 = parts[((size_t)1*128 + p)*8 + 4];
        float* o = wsP + ((size_t)b*NN + n0 + p)*PSTRIDE + mt*5;
        o[0] = r0.x + r1.x;
        o[1] = r0.y + r1.y;
        o[2] = r0.z + r1.z;
        o[3] = r0.w + r1.w;
        o[4] = e0 + e1;
    } else if(tid < 256){
        int p = tid - 128;
        int wcsel = p >> 6, pp = p & 63;
        float s0=0.f,s1=0.f,s2=0.f,s3=0.f,s4=0.f;
        #pragma unroll
        for(int wrv=0; wrv<4; ++wrv){
            #pragma unroll
            for(int lh2=0; lh2<4; ++lh2){
                const float* cp = parts + COLOFF + (((size_t)(wrv*2+wcsel)*4 + lh2)*64 + pp)*6;
                float2 a = *(const float2*)cp;
                float2 q = *(const float2*)(cp+2);
                s0 += a.x; s1 += a.y; s2 += q.x; s3 += q.y; s4 += cp[4];
            }
        }
        float* o = wsP + ((size_t)(BB*NN) + (size_t)b*NN + m0 + p)*PSTRIDE + nt*5;
        o[0]=s0; o[1]=s1; o[2]=s2; o[3]=s3; o[4]=s4;
    }
}

// Window refinement + finalize, wave-per-query: 4 independent queries per block,
// ZERO block barriers (wave-synchronous LDS), fdot2 dots, DPP reductions.
__global__ __launch_bounds__(256) void k_win2(
        const __hip_bfloat16* __restrict__ f1b, const __hip_bfloat16* __restrict__ f2b,
        const hf* __restrict__ xf1t, const hf* __restrict__ xf2t,
        const float* __restrict__ wsP,
        float* __restrict__ o_g1, float* __restrict__ o_g1n, float* __restrict__ o_std1,
        float* __restrict__ o_g2, float* __restrict__ o_g2n, float* __restrict__ o_std2,
        float* __restrict__ o_w1, float* __restrict__ o_wstd1,
        float* __restrict__ o_w2, float* __restrict__ o_wstd2,
        float* __restrict__ o_valid,
        const int* __restrict__ h1I, const int* __restrict__ w1I,
        const int* __restrict__ h2I, const int* __restrict__ w2I){
    int tid = threadIdx.x;
    int lane = tid & 63, wid = tid >> 6;
    int gid = blockIdx.x*4 + wid;
    int dir = gid / (BB*NN);
    int bn  = gid % (BB*NN);
    int b   = bn / NN;
    const __hip_bfloat16* fQ = dir ? f2b : f1b;
    const hf* fmapT          = dir ? xf1t : xf2t;
    const int* hI            = dir ? h1I  : h2I;
    const int* wI            = dir ? w1I  : w2I;
    float* outW              = dir ? o_w2 : o_w1;
    float* outStd            = dir ? o_wstd2 : o_wstd1;
    float* oG                = dir ? o_g2  : o_g1;
    float* oGn               = dir ? o_g2n : o_g1n;
    float* oSd               = dir ? o_std2: o_std1;

    __shared__ float dlS[4][128];
    float* dl = dlS[wid];

    // ---- finalize this point's g/gn/std from tile partials (wave-local k_red) ----
    const float* basep = wsP + ((size_t)dir*(BB*NN) + bn)*PSTRIDE;
    dl[lane] = basep[lane];
    if(lane < 56) dl[64+lane] = basep[64+lane];
    float partc = 0.f;
    if(lane < 5){
        #pragma unroll
        for(int m=0;m<NTILE;m++) partc += dl[m*5+lane];
    }
    float S  = __shfl(partc, 0);
    float AX = __shfl(partc, 1);
    float AY = __shfl(partc, 2);
    float AXX= __shfl(partc, 3);
    float AYY= __shfl(partc, 4);
    float hfv = (float)hI[0], wfv = (float)wI[0];
    float gdx = AX/S, gdy = AY/S;
    float gx = gdx*(2.0f/(wfv-1.0f)) - 1.0f;
    float gy = gdy*(2.0f/(hfv-1.0f)) - 1.0f;
    if(lane == 0){
        float vx0 = AXX/S - gx*gx, vy0 = AYY/S - gy*gy;
        float sd0 = sqrtf(fmaxf(vx0,1e-6f)) + sqrtf(fmaxf(vy0,1e-6f));
        oG[(size_t)bn*2+0]=gdx; oG[(size_t)bn*2+1]=gdy;
        oGn[(size_t)bn*2+0]=gx; oGn[(size_t)bn*2+1]=gy;
        oSd[bn]=sd0;
        o_valid[gid]=1.0f;
    }

    // ---- window phase 1: 120 pixel-dots, 8 pixels/iter (15 iters), no barriers ----
    int xb, yb;
    {   int t1; float tw;
        bsetup(gx - 0.125f, WW, xb, t1, tw);
        bsetup(gy - 0.125f, HH, yb, t1, tw);
    }
    int cg  = lane & 7;    // 16-channel group
    int sub = lane >> 3;   // pixel sub-index

    h2 fq2[8];
    {
        const uint* q = (const uint*)(fQ + (size_t)bn*CC) + cg*8;
        #pragma unroll
        for(int d=0; d<8; ++d){
            uint u = q[d];
            float lo = __uint_as_float(u << 16);
            float hi = __uint_as_float(u & 0xffff0000u);
            fq2[d].x = (hf)lo; fq2[d].y = (hf)hi;
        }
    }

    const hf* base = fmapT + (size_t)b*HW*CC;
    #pragma unroll 5
    for(int it=0; it<15; ++it){
        int p = it*8 + sub;    // 120 = 15*8, no tail
        int ky = p / XN, kx = p - ky*XN;
        int py = yb + ky; if(py > HH-1) py = HH-1;
        int px = xb + kx; if(px > WW-1) px = WW-1;
        const uint4* row = (const uint4*)(base + (size_t)(py*WW + px)*CC) + cg*2;
        union { uint4 u[2]; h2 v[8]; } U;
        U.u[0] = row[0]; U.u[1] = row[1];
        float s = 0.f;
        #pragma unroll
        for(int d=0; d<8; ++d) s = FDOT2(fq2[d], U.v[d], s);
        s = red8_add(s);
        if(cg==0) dl[p] = s;
    }

    // ---- phase 2: 81 samples, <=2 per lane, wave-reduce ----
    float l0, wx0c, wy0c;
    {
        int i = lane % 9, j = lane / 9;
        wx0c = gx + (-0.125f + 0.03125f*(float)i);
        wy0c = gy + (-0.125f + 0.03125f*(float)j);
        int x0,x1,y0,y1; float wx,wy;
        bsetup(wx0c, WW, x0,x1,wx);
        bsetup(wy0c, HH, y0,y1,wy);
        int r0 = (y0-yb)*XN - xb, r1 = (y1-yb)*XN - xb;
        float d00=dl[r0+x0], d01=dl[r0+x1], d10=dl[r1+x0], d11=dl[r1+x1];
        l0 = d00*(1.f-wx)*(1.f-wy) + d01*wx*(1.f-wy) + d10*(1.f-wx)*wy + d11*wx*wy;
    }
    float l1 = -INFINITY, wx1c = 0.f, wy1c = 0.f;
    if(lane < SS-64){
        int s1 = 64 + lane;
        int i = s1 % 9, j = s1 / 9;
        wx1c = gx + (-0.125f + 0.03125f*(float)i);
        wy1c = gy + (-0.125f + 0.03125f*(float)j);
        int x0,x1,y0,y1; float wx,wy;
        bsetup(wx1c, WW, x0,x1,wx);
        bsetup(wy1c, HH, y0,y1,wy);
        int r0 = (y0-yb)*XN - xb, r1 = (y1-yb)*XN - xb;
        float d00=dl[r0+x0], d01=dl[r0+x1], d10=dl[r1+x0], d11=dl[r1+x1];
        l1 = d00*(1.f-wx)*(1.f-wy) + d01*wx*(1.f-wy) + d10*(1.f-wx)*wy + d11*wx*wy;
    }

    float M = red64_max(fmaxf(l0, l1));
    float w0 = __expf(l0 - M);
    float w1 = (lane < SS-64) ? __expf(l1 - M) : 0.f;
    float v0 = red64_add(w0 + w1);
    float v1 = red64_add(w0*wx0c + w1*wx1c);
    float v2 = red64_add(w0*wy0c + w1*wy1c);
    float v3 = red64_add(w0*wx0c*wx0c + w1*wx1c*wx1c);
    float v4 = red64_add(w0*wy0c*wy0c + w1*wy1c*wy1c);
    if(lane == 0){
        float ex = v1/v0, ey = v2/v0;
        float vx = v3/v0 - ex*ex;
        float vy = v4/v0 - ey*ey;
        float sd = sqrtf(fmaxf(vx,1e-6f)) + sqrtf(fmaxf(vy,1e-6f));
        outW[(size_t)bn*2+0] = (ex+1.0f)*0.5f*(wfv-1.0f);
        outW[(size_t)bn*2+1] = (ey+1.0f)*0.5f*(hfv-1.0f);
        outStd[bn] = sd;
    }
}

extern "C" void kernel_launch(void* const* d_in, const int* in_sizes, int n_in,
                              void* d_out, int out_size, void* d_ws, size_t ws_size,
                              hipStream_t stream){
    const float* xf1 = (const float*)d_in[0];
    const float* xf2 = (const float*)d_in[1];
    const float* c1n = (const float*)d_in[2];
    const float* c2n = (const float*)d_in[3];
    const int* h1 = (const int*)d_in[4];
    const int* w1 = (const int*)d_in[5];
    const int* h2 = (const int*)d_in[6];
    const int* w2 = (const int*)d_in[7];
    float* out = (float*)d_out;

    hf* xf1r = (hf*)d_ws;                               // B*HW*C f16 raw transposed
    hf* xf2r = xf1r + (size_t)BB*HW*CC;
    hf* xf1t = xf2r + (size_t)BB*HW*CC;                 // B*HW*C f16 T*normalized
    hf* xf2t = xf1t + (size_t)BB*HW*CC;
    __hip_bfloat16* f1b = (__hip_bfloat16*)(xf2t + (size_t)BB*HW*CC);   // B*N*C bf16
    __hip_bfloat16* f2b = f1b + (size_t)BB*NN*CC;
    float* wsP = (float*)(f2b + (size_t)BB*NN*CC);      // [2][BB*NN][PSTRIDE] f32

    float* o_coord1 = out + 0;
    float* o_coord2 = out + 12288;
    float* o_g1     = out + 24576;
    float* o_g2     = out + 36864;
    float* o_w1     = out + 49152;
    float* o_w2     = out + 61440;
    float* o_g1n    = out + 73728;
    float* o_g2n    = out + 86016;
    float* o_std1   = out + 98304;
    float* o_std2   = out + 104448;
    float* o_wstd1  = out + 110592;
    float* o_wstd2  = out + 116736;
    float* o_valid  = out + 122880;

    hipLaunchKernelGGL(k_normT, dim3(2*BB*(HW/32)), dim3(256), 0, stream,
                       xf1, xf2, xf1r, xf2r, xf1t, xf2t);
    hipLaunchKernelGGL(k_feats, dim3(2*BB*NN/4), dim3(256), 0, stream,
                       xf1r, xf2r, c1n, c2n, f1b, f2b, o_coord1, o_coord2, h1, w1, h2, w2);
    hipLaunchKernelGGL(k_corr, dim3(BB*NTILE*NTILE), dim3(512), 0, stream,
                       f1b, f2b, c1n, c2n, wsP, h1, w1, h2, w2);
    hipLaunchKernelGGL(k_win2, dim3(2*BB*NN/4), dim3(256), 0, stream,
                       f1b, f2b, xf1t, xf2t, wsP,
                       o_g1, o_g1n, o_std1, o_g2, o_g2n, o_std2,
                       o_w1, o_wstd1, o_w2, o_wstd2, o_valid, h1, w1, h2, w2);
}